// Round 3
// baseline (626.595 us; speedup 1.0000x reference)
//
#include <hip/hip_runtime.h>

// ProbOhemCrossEntropy2d on MI355X.
// pred [8,19,768,768] f32, target [8,768,768] i32 -> scalar f32 loss.
//
// Plan:
//  k_init    : zero meta region of ws (hists + scalars)
//  k_pass1   : per-pixel log-softmax -> prob bits (u32) + logp (f32) to ws,
//              fused level-1 histogram (bits>>21, 2048 bins) + num_valid
//  k_scan(1) : select level-1 bin containing k-th smallest
//  k_refine2 : histogram (bits>>10)&2047 for elements in selected bin
//  k_scan(2) : select level-2 bin
//  k_refine3 : histogram bits&1023 for elements matching top-22 bits
//  k_scan(3) : exact kth bits -> threshold = max(kth, 0.7), do_ohem flag
//  k_final   : masked loss sum + count (block-reduced, atomics)
//  k_finalize: loss = sum / max(count,1) -> d_out[0]

#define BB 8
#define CC 19
#define HH 768
#define WW 768
#define HWSZ (HH * WW)          // 589824
#define NPIX (BB * HWSZ)        // 4718592
#define KSEL 262144
#define IGNORE_LBL 255
#define THR 0.7f

// ws layout (u32 words):
// [0] num_valid  [1] k_rem  [2] sel_bits  [3] kept_count
// [4] do_ohem    [5] threshold (float bits)
// [6..7] loss_sum (double)
// [8 .. 8+2048)      hist1
// [2056 .. +2048)    hist2
// [4104 .. +1024)    hist3
// [8192 .. +NPIX)    prob_bits
// then NPIX floats   logp (optional, if ws_size allows)
#define HIST1_OFF 8
#define HIST2_OFF (HIST1_OFF + 2048)
#define HIST3_OFF (HIST2_OFF + 2048)
#define META_WORDS 8192
#define PROB_OFF META_WORDS

__global__ __launch_bounds__(256) void k_init(unsigned* __restrict__ ws) {
    for (int i = threadIdx.x; i < META_WORDS; i += 256) ws[i] = 0u;
}

__global__ __launch_bounds__(256) void k_pass1(const float* __restrict__ pred,
                                               const int* __restrict__ target,
                                               unsigned* __restrict__ ws,
                                               float* __restrict__ logp_out,
                                               int has_logp) {
    __shared__ unsigned hist[2048];
    __shared__ unsigned snv;
    for (int i = threadIdx.x; i < 2048; i += 256) hist[i] = 0u;
    if (threadIdx.x == 0) snv = 0u;
    __syncthreads();

    int g = blockIdx.x * 256 + threadIdx.x;
    int pix0 = g * 4;
    int b = pix0 / HWSZ;
    int hw = pix0 - b * HWSZ;
    const float* base = pred + (size_t)b * ((size_t)CC * HWSZ) + hw;

    float x[CC][4];
#pragma unroll
    for (int c = 0; c < CC; ++c) {
        float4 v = *reinterpret_cast<const float4*>(base + (size_t)c * HWSZ);
        x[c][0] = v.x; x[c][1] = v.y; x[c][2] = v.z; x[c][3] = v.w;
    }
    int4 t4 = *reinterpret_cast<const int4*>(target + pix0);
    int tt[4] = {t4.x, t4.y, t4.z, t4.w};

    unsigned pbits[4];
    float plogp[4];
    int nv = 0;
#pragma unroll
    for (int p = 0; p < 4; ++p) {
        int t = tt[p];
        bool valid = (t != IGNORE_LBL);
        nv += valid ? 1 : 0;
        int tc = valid ? t : 0;
        float m = x[0][p];
#pragma unroll
        for (int c = 1; c < CC; ++c) m = fmaxf(m, x[c][p]);
        float s = 0.0f;
        float xt = x[0][p];
#pragma unroll
        for (int c = 0; c < CC; ++c) {
            float v = x[c][p];
            s += expf(v - m);
            xt = (c == tc) ? v : xt;   // cndmask, avoids runtime-indexed array
        }
        float lp = xt - m - logf(s);
        float pr = valid ? expf(lp) : 1.0f;
        pbits[p] = __float_as_uint(pr);
        plogp[p] = lp;
        atomicAdd(&hist[pbits[p] >> 21], 1u);
    }
    *reinterpret_cast<uint4*>(ws + PROB_OFF + pix0) =
        make_uint4(pbits[0], pbits[1], pbits[2], pbits[3]);
    if (has_logp)
        *reinterpret_cast<float4*>(logp_out + pix0) =
            make_float4(plogp[0], plogp[1], plogp[2], plogp[3]);
    atomicAdd(&snv, (unsigned)nv);
    __syncthreads();
    for (int i = threadIdx.x; i < 2048; i += 256) {
        unsigned v = hist[i];
        if (v) atomicAdd(ws + HIST1_OFF + i, v);
    }
    if (threadIdx.x == 0) atomicAdd(ws + 0, snv);
}

// One block, 256 threads. Finds the bin containing the k_rem-th smallest.
__global__ __launch_bounds__(256) void k_scan(unsigned* __restrict__ ws, int level) {
    const unsigned* hist;
    int nbins, shift;
    if (level == 1)      { hist = ws + HIST1_OFF; nbins = 2048; shift = 21; }
    else if (level == 2) { hist = ws + HIST2_OFF; nbins = 2048; shift = 10; }
    else                 { hist = ws + HIST3_OFF; nbins = 1024; shift = 0;  }
    int chunk = nbins >> 8;
    int t = threadIdx.x;
    __shared__ unsigned csum[256];
    unsigned s = 0;
    for (int j = 0; j < chunk; ++j) s += hist[t * chunk + j];
    csum[t] = s;
    unsigned krem = (level == 1) ? (unsigned)KSEL : ws[1];
    unsigned selprev = (level == 1) ? 0u : ws[2];
    unsigned nvv = ws[0];
    for (int off = 1; off < 256; off <<= 1) {
        __syncthreads();
        unsigned add = (t >= off) ? csum[t - off] : 0u;
        __syncthreads();
        csum[t] += add;
    }
    unsigned incl = csum[t];
    unsigned excl = incl - s;
    bool own = (excl < krem) && (krem <= incl);
    __syncthreads();   // all reads of ws[1]/ws[2] done before the owner writes
    if (own) {
        unsigned running = excl;
        int bin = 0;
        unsigned cb = excl;
        for (int j = 0; j < chunk; ++j) {
            unsigned h = hist[t * chunk + j];
            if (running + h >= krem) { bin = t * chunk + j; cb = running; break; }
            running += h;
        }
        unsigned sel = selprev | (((unsigned)bin) << shift);
        ws[2] = sel;
        ws[1] = krem - cb;
        if (level == 3) {
            float kth = __uint_as_float(sel);
            reinterpret_cast<float*>(ws)[5] = fmaxf(kth, THR);
            ws[4] = (nvv > 0u && nvv >= (unsigned)KSEL) ? 1u : 0u;
        }
    }
}

// 1152 blocks x 256 threads x 4 uint4 iters covers NPIX/4 uint4 elements exactly.
__global__ __launch_bounds__(256) void k_refine(unsigned* __restrict__ ws, int level) {
    __shared__ unsigned hist[2048];
    int nb = (level == 2) ? 2048 : 1024;
    for (int i = threadIdx.x; i < nb; i += 256) hist[i] = 0u;
    __syncthreads();
    unsigned sel = ws[2];
    const uint4* pb = reinterpret_cast<const uint4*>(ws + PROB_OFF);
    int idx = blockIdx.x * 256 + threadIdx.x;
    const int stride = 1152 * 256;
#pragma unroll
    for (int it = 0; it < 4; ++it) {
        uint4 v = pb[idx + it * stride];
        unsigned arr[4] = {v.x, v.y, v.z, v.w};
#pragma unroll
        for (int p = 0; p < 4; ++p) {
            unsigned bits = arr[p];
            if (level == 2) {
                if ((bits >> 21) == (sel >> 21))
                    atomicAdd(&hist[(bits >> 10) & 2047u], 1u);
            } else {
                if ((bits >> 10) == (sel >> 10))
                    atomicAdd(&hist[bits & 1023u], 1u);
            }
        }
    }
    __syncthreads();
    unsigned* gh = ws + ((level == 2) ? HIST2_OFF : HIST3_OFF);
    for (int i = threadIdx.x; i < nb; i += 256) {
        unsigned v = hist[i];
        if (v) atomicAdd(gh + i, v);
    }
}

__global__ __launch_bounds__(256) void k_final(unsigned* __restrict__ ws,
                                               const float* __restrict__ logp,
                                               const int* __restrict__ target,
                                               int has_logp) {
    float thr = __uint_as_float(ws[5]);
    unsigned do_ohem = ws[4];
    int g = blockIdx.x * 256 + threadIdx.x;
    int pix0 = g * 4;
    uint4 pv = *reinterpret_cast<const uint4*>(ws + PROB_OFF + pix0);
    int4 t4 = *reinterpret_cast<const int4*>(target + pix0);
    float4 lp4 = make_float4(0.f, 0.f, 0.f, 0.f);
    if (has_logp) lp4 = *reinterpret_cast<const float4*>(logp + pix0);
    unsigned pb[4] = {pv.x, pv.y, pv.z, pv.w};
    int tt[4] = {t4.x, t4.y, t4.z, t4.w};
    float lpv[4] = {lp4.x, lp4.y, lp4.z, lp4.w};
    float ls = 0.0f;
    unsigned lc = 0;
#pragma unroll
    for (int p = 0; p < 4; ++p) {
        bool valid = (tt[p] != IGNORE_LBL);
        float pr = __uint_as_float(pb[p]);
        bool kept = (pr <= thr);
        bool vf = do_ohem ? (valid && kept) : valid;
        float pl = has_logp ? (-lpv[p]) : (-logf(fmaxf(pr, 1e-37f)));
        if (vf) { ls += pl; lc += 1u; }
    }
    __shared__ float ssum;
    __shared__ unsigned scnt;
    if (threadIdx.x == 0) { ssum = 0.0f; scnt = 0u; }
    __syncthreads();
    for (int off = 32; off > 0; off >>= 1) {
        ls += __shfl_down(ls, off);
        lc += __shfl_down(lc, off);
    }
    if ((threadIdx.x & 63) == 0) {
        atomicAdd(&ssum, ls);
        atomicAdd(&scnt, lc);
    }
    __syncthreads();
    if (threadIdx.x == 0) {
        atomicAdd(reinterpret_cast<double*>(ws + 6), (double)ssum);
        atomicAdd(ws + 3, scnt);
    }
}

__global__ void k_finalize(const unsigned* __restrict__ ws, float* __restrict__ out) {
    if (threadIdx.x == 0 && blockIdx.x == 0) {
        double s = *reinterpret_cast<const double*>(ws + 6);
        unsigned c = ws[3];
        unsigned d = (c > 0u) ? c : 1u;
        out[0] = (float)(s / (double)d);
    }
}

extern "C" void kernel_launch(void* const* d_in, const int* in_sizes, int n_in,
                              void* d_out, int out_size, void* d_ws, size_t ws_size,
                              hipStream_t stream) {
    const float* pred = (const float*)d_in[0];
    const int* target = (const int*)d_in[1];
    unsigned* ws = (unsigned*)d_ws;
    float* out = (float*)d_out;

    size_t need_full = ((size_t)META_WORDS + (size_t)NPIX) * 4u + (size_t)NPIX * 4u;
    int has_logp = (ws_size >= need_full) ? 1 : 0;
    float* logp = reinterpret_cast<float*>(ws + META_WORDS + NPIX);

    k_init<<<1, 256, 0, stream>>>(ws);
    k_pass1<<<NPIX / 1024, 256, 0, stream>>>(pred, target, ws, logp, has_logp);
    k_scan<<<1, 256, 0, stream>>>(ws, 1);
    k_refine<<<1152, 256, 0, stream>>>(ws, 2);
    k_scan<<<1, 256, 0, stream>>>(ws, 2);
    k_refine<<<1152, 256, 0, stream>>>(ws, 3);
    k_scan<<<1, 256, 0, stream>>>(ws, 3);
    k_final<<<NPIX / 1024, 256, 0, stream>>>(ws, logp, target, has_logp);
    k_finalize<<<1, 64, 0, stream>>>(ws, out);
}

// Round 4
// 579.660 us; speedup vs baseline: 1.0810x; 1.0810x over previous
//
#include <hip/hip_runtime.h>

// ProbOhemCrossEntropy2d on MI355X — round 4.
// pred [8,19,768,768] f32, target [8,768,768] i32 -> scalar f32 loss.
//
// 6 dispatches:
//  k_init     : zero hist/meta words
//  k_pass1    : grid-stride (1152 blocks) log-softmax -> prob bits + LDS hist1
//               (flushed once per block) + num_valid (1 atomic/wave)
//  k_refine<2>: block-local scan of hist1 (prologue) -> hist2
//  k_refine<3>: prologue scans hist1+hist2 -> hist3
//  k_final    : prologue scans hist1+2+3 -> exact kth -> threshold;
//               masked loss sum (-logf(prob)) + count
//  k_finalize : loss = sum / max(count,1)

#define CC 19
#define HWSZ 589824            // 768*768
#define NPIX 4718592           // 8*HWSZ
#define KSEL 262144
#define IGNORE_LBL 255
#define THR 0.7f
#define NBLK 1152
#define ITERS 4                // NPIX/4 / (NBLK*256) == 4 exactly

// ws layout (u32 words):
// [0] num_valid  [3] kept_count  [6..7] loss_sum (double)
// [8..+2048) hist1  [2056..+2048) hist2  [4104..+1024) hist3
// [8192..+NPIX) prob bits
#define HIST1_OFF 8
#define HIST2_OFF (HIST1_OFF + 2048)
#define HIST3_OFF (HIST2_OFF + 2048)
#define META_WORDS 8192
#define PROB_OFF META_WORDS

__global__ __launch_bounds__(256) void k_init(unsigned* __restrict__ ws) {
    for (int i = threadIdx.x; i < META_WORDS; i += 256) ws[i] = 0u;
}

// Block-local radix-select step: given global histogram gh[NBINS] and the
// rank krem_in, find the bin holding the krem_in-th smallest; accumulate
// bin<<shift into sel_io and output the rank within that bin. Pure function
// of (gh, krem_in) -> identical result in every block.
template <int NBINS>
__device__ __forceinline__ void find_bin(const unsigned* __restrict__ gh,
                                         unsigned krem_in, int shift,
                                         unsigned& sel_io, unsigned& krem_out) {
    constexpr int CHUNK = NBINS / 256;
    __shared__ unsigned csum[256];
    __shared__ unsigned sb[2];
    const int t = threadIdx.x;
    __syncthreads();                 // protect csum/sb reuse across calls
    unsigned loc[CHUNK];
    unsigned s = 0;
#pragma unroll
    for (int j = 0; j < CHUNK; ++j) { loc[j] = gh[t * CHUNK + j]; s += loc[j]; }
    csum[t] = s;
    for (int off = 1; off < 256; off <<= 1) {
        __syncthreads();
        unsigned add = (t >= off) ? csum[t - off] : 0u;
        __syncthreads();
        csum[t] += add;
    }
    unsigned incl = csum[t];
    unsigned excl = incl - s;
    if (excl < krem_in && krem_in <= incl) {   // exactly one owner thread
        unsigned run = excl;
        unsigned bin = 0;
        bool found = false;
#pragma unroll
        for (int j = 0; j < CHUNK; ++j) {
            unsigned nrun = run + loc[j];
            if (!found && nrun >= krem_in) { bin = (unsigned)(t * CHUNK + j); found = true; }
            if (!found) run = nrun;
        }
        sb[0] = bin;
        sb[1] = krem_in - run;
    }
    __syncthreads();
    sel_io |= sb[0] << shift;
    krem_out = sb[1];
}

__global__ __launch_bounds__(256) void k_pass1(const float* __restrict__ pred,
                                               const int* __restrict__ target,
                                               unsigned* __restrict__ ws) {
    __shared__ unsigned hist[2048];
    for (int i = threadIdx.x; i < 2048; i += 256) hist[i] = 0u;
    __syncthreads();

    unsigned nv = 0;
    for (int it = 0; it < ITERS; ++it) {
        int q = it * (NBLK * 256) + blockIdx.x * 256 + threadIdx.x;  // quad index
        int pix0 = q * 4;
        int b = pix0 / HWSZ;
        int hw = pix0 - b * HWSZ;
        const float* base = pred + (size_t)b * ((size_t)CC * HWSZ) + hw;

        float x[CC][4];
#pragma unroll
        for (int c = 0; c < CC; ++c) {
            float4 v = *reinterpret_cast<const float4*>(base + (size_t)c * HWSZ);
            x[c][0] = v.x; x[c][1] = v.y; x[c][2] = v.z; x[c][3] = v.w;
        }
        int4 t4 = *reinterpret_cast<const int4*>(target + pix0);
        int tt[4] = {t4.x, t4.y, t4.z, t4.w};

        unsigned pb[4];
#pragma unroll
        for (int p = 0; p < 4; ++p) {
            int t = tt[p];
            bool valid = (t != IGNORE_LBL);
            nv += valid ? 1u : 0u;
            int tc = valid ? t : 0;
            float m = x[0][p];
#pragma unroll
            for (int c = 1; c < CC; ++c) m = fmaxf(m, x[c][p]);
            float s = 0.0f;
            float xt = x[0][p];
#pragma unroll
            for (int c = 0; c < CC; ++c) {
                float v = x[c][p];
                s += expf(v - m);
                xt = (c == tc) ? v : xt;   // cndmask, no runtime-indexed array
            }
            float lp = xt - m - logf(s);
            float pr = valid ? expf(lp) : 1.0f;
            pb[p] = __float_as_uint(pr);
            atomicAdd(&hist[pb[p] >> 21], 1u);
        }
        *reinterpret_cast<uint4*>(ws + PROB_OFF + pix0) =
            make_uint4(pb[0], pb[1], pb[2], pb[3]);
    }

    // num_valid: wave-reduce then 1 atomic per wave
    for (int off = 32; off; off >>= 1) nv += __shfl_down(nv, off);
    if ((threadIdx.x & 63) == 0) atomicAdd(ws + 0, nv);

    __syncthreads();
    // flush LDS hist once per block; rotate start to spread hot-bin atomics
    int rot = (blockIdx.x & 7) << 8;
    for (int i = threadIdx.x; i < 2048; i += 256) {
        int idx = (i + rot) & 2047;
        unsigned v = hist[idx];
        if (v) atomicAdd(ws + HIST1_OFF + idx, v);
    }
}

template <int LEVEL>
__global__ __launch_bounds__(256) void k_refine(unsigned* __restrict__ ws) {
    constexpr int NB = (LEVEL == 2) ? 2048 : 1024;
    __shared__ unsigned hist[NB];
    for (int i = threadIdx.x; i < NB; i += 256) hist[i] = 0u;
    // find_bin's leading __syncthreads covers the hist zero above
    unsigned sel = 0, krem = 0;
    find_bin<2048>(ws + HIST1_OFF, (unsigned)KSEL, 21, sel, krem);
    if (LEVEL == 3) find_bin<2048>(ws + HIST2_OFF, krem, 10, sel, krem);

    const uint4* pbv = reinterpret_cast<const uint4*>(ws + PROB_OFF);
    for (int it = 0; it < ITERS; ++it) {
        int q = it * (NBLK * 256) + blockIdx.x * 256 + threadIdx.x;
        uint4 v = pbv[q];
        unsigned a[4] = {v.x, v.y, v.z, v.w};
#pragma unroll
        for (int p = 0; p < 4; ++p) {
            unsigned bits = a[p];
            if (LEVEL == 2) {
                if ((bits >> 21) == (sel >> 21))
                    atomicAdd(&hist[(bits >> 10) & 2047u], 1u);
            } else {
                if ((bits >> 10) == (sel >> 10))
                    atomicAdd(&hist[bits & 1023u], 1u);
            }
        }
    }
    __syncthreads();
    unsigned* gh = ws + ((LEVEL == 2) ? HIST2_OFF : HIST3_OFF);
    int rot = (blockIdx.x & 3) << 8;
    for (int i = threadIdx.x; i < NB; i += 256) {
        int idx = (i + rot) & (NB - 1);
        unsigned v = hist[idx];
        if (v) atomicAdd(gh + idx, v);
    }
}

__global__ __launch_bounds__(256) void k_final(unsigned* __restrict__ ws,
                                               const int* __restrict__ target) {
    unsigned sel = 0, krem = 0;
    find_bin<2048>(ws + HIST1_OFF, (unsigned)KSEL, 21, sel, krem);
    find_bin<2048>(ws + HIST2_OFF, krem, 10, sel, krem);
    find_bin<1024>(ws + HIST3_OFF, krem, 0, sel, krem);
    float thr = fmaxf(__uint_as_float(sel), THR);
    unsigned nvv = ws[0];
    bool do_ohem = (nvv > 0u) && (nvv >= (unsigned)KSEL);

    const uint4* pbv = reinterpret_cast<const uint4*>(ws + PROB_OFF);
    float ls = 0.0f;
    unsigned lc = 0;
    for (int it = 0; it < ITERS; ++it) {
        int q = it * (NBLK * 256) + blockIdx.x * 256 + threadIdx.x;
        int pix0 = q * 4;
        uint4 v = pbv[q];
        int4 t4 = *reinterpret_cast<const int4*>(target + pix0);
        unsigned a[4] = {v.x, v.y, v.z, v.w};
        int tt[4] = {t4.x, t4.y, t4.z, t4.w};
#pragma unroll
        for (int p = 0; p < 4; ++p) {
            bool valid = (tt[p] != IGNORE_LBL);
            float pr = __uint_as_float(a[p]);
            bool kept = (pr <= thr);
            bool vf = do_ohem ? (valid && kept) : valid;
            if (vf) { ls += -logf(pr); lc += 1u; }   // pr = exp(logp_t), valid => pr<=1
        }
    }
    // wave reduce, then block reduce via LDS, then global atomics
    for (int off = 32; off; off >>= 1) {
        ls += __shfl_down(ls, off);
        lc += __shfl_down(lc, off);
    }
    __shared__ float wsum[4];
    __shared__ unsigned wcnt[4];
    if ((threadIdx.x & 63) == 0) {
        wsum[threadIdx.x >> 6] = ls;
        wcnt[threadIdx.x >> 6] = lc;
    }
    __syncthreads();
    if (threadIdx.x == 0) {
        float bs = wsum[0] + wsum[1] + wsum[2] + wsum[3];
        unsigned bc = wcnt[0] + wcnt[1] + wcnt[2] + wcnt[3];
        atomicAdd(reinterpret_cast<double*>(ws + 6), (double)bs);
        atomicAdd(ws + 3, bc);
    }
}

__global__ void k_finalize(const unsigned* __restrict__ ws, float* __restrict__ out) {
    if (threadIdx.x == 0 && blockIdx.x == 0) {
        double s = *reinterpret_cast<const double*>(ws + 6);
        unsigned c = ws[3];
        unsigned d = (c > 0u) ? c : 1u;
        out[0] = (float)(s / (double)d);
    }
}

extern "C" void kernel_launch(void* const* d_in, const int* in_sizes, int n_in,
                              void* d_out, int out_size, void* d_ws, size_t ws_size,
                              hipStream_t stream) {
    const float* pred = (const float*)d_in[0];
    const int* target = (const int*)d_in[1];
    unsigned* ws = (unsigned*)d_ws;
    float* out = (float*)d_out;

    k_init<<<1, 256, 0, stream>>>(ws);
    k_pass1<<<NBLK, 256, 0, stream>>>(pred, target, ws);
    k_refine<2><<<NBLK, 256, 0, stream>>>(ws);
    k_refine<3><<<NBLK, 256, 0, stream>>>(ws);
    k_final<<<NBLK, 256, 0, stream>>>(ws, target);
    k_finalize<<<1, 64, 0, stream>>>(ws, out);
}

// Round 8
// 511.721 us; speedup vs baseline: 1.2245x; 1.1328x over previous
//
#include <hip/hip_runtime.h>

// ProbOhemCrossEntropy2d on MI355X — round 5 kernel (resubmit #3; infra failures).
// pred [8,19,768,768] f32, target [8,768,768] i32 -> scalar f32 loss.
//
// Key insight: threshold = max(kth_smallest_prob, 0.7). If count(prob <
// 0.625) >= k (checkable from the level-1 histogram: bins 0..504), then
// kth < 0.7 so threshold == 0.7f exactly. pass1 speculatively accumulates
// the loss for threshold==0.7 (spec_*) and the no-OHEM fallback (tot_*);
// the selection/refine/final-scan kernels early-exit. The general path
// (kth > 0.7) still runs the exact 3-level radix select + full scan.
//
// 6 dispatches: k_init, k_pass1, k_refine<2>, k_refine<3>, k_final, k_finalize.

#define CC 19
#define HWSZ 589824            // 768*768
#define NPIX 4718592           // 8*HWSZ
#define KSEL 262144
#define IGNORE_LBL 255
#define THR 0.7f
#define NBLK 1152
#define ITERS 4                // NPIX/4 / (NBLK*256) == 4 exactly
#define BIN_07 505             // 0x3F333333 >> 21

// ws layout (u32 words):
// [1] spec_cnt  [2] tot_cnt (== num_valid)  [3] slow_cnt  [4] early_flag
// [6..7] slow_sum (double)  [8..9] spec_sum (double)  [10..11] tot_sum (double)
// [16..+2048) hist1  [..+2048) hist2  [..+1024) hist3
// [8192..+NPIX) prob bits
#define W_SPEC_CNT 1
#define W_TOT_CNT 2
#define W_SLOW_CNT 3
#define W_EARLY 4
#define W_SLOW_SUM 6
#define W_SPEC_SUM 8
#define W_TOT_SUM 10
#define HIST1_OFF 16
#define HIST2_OFF (HIST1_OFF + 2048)
#define HIST3_OFF (HIST2_OFF + 2048)
#define META_WORDS 8192
#define PROB_OFF META_WORDS

__global__ __launch_bounds__(256) void k_init(unsigned* __restrict__ ws) {
    for (int i = threadIdx.x; i < META_WORDS; i += 256) ws[i] = 0u;
}

// True iff threshold is exactly 0.7f (conservative: counts bins [0,505) of
// hist1, i.e. prob < 0.625). Pure function of hist1 -> same answer in every
// block of every kernel. All 256 threads participate; result valid in all.
__device__ __forceinline__ bool early_thr(const unsigned* __restrict__ gh) {
    unsigned v = 0;
    for (int i = threadIdx.x; i < BIN_07; i += 256) v += gh[i];
    for (int off = 32; off; off >>= 1) v += __shfl_down(v, off);
    __shared__ unsigned cw[4];
    if ((threadIdx.x & 63) == 0) cw[threadIdx.x >> 6] = v;
    __syncthreads();
    unsigned c_lo = cw[0] + cw[1] + cw[2] + cw[3];
    __syncthreads();
    return c_lo >= (unsigned)KSEL;
}

// Block-local radix-select step (pure function of (gh, krem_in)).
template <int NBINS>
__device__ __forceinline__ void find_bin(const unsigned* __restrict__ gh,
                                         unsigned krem_in, int shift,
                                         unsigned& sel_io, unsigned& krem_out) {
    constexpr int CHUNK = NBINS / 256;
    __shared__ unsigned csum[256];
    __shared__ unsigned sb[2];
    const int t = threadIdx.x;
    __syncthreads();
    unsigned loc[CHUNK];
    unsigned s = 0;
#pragma unroll
    for (int j = 0; j < CHUNK; ++j) { loc[j] = gh[t * CHUNK + j]; s += loc[j]; }
    csum[t] = s;
    for (int off = 1; off < 256; off <<= 1) {
        __syncthreads();
        unsigned add = (t >= off) ? csum[t - off] : 0u;
        __syncthreads();
        csum[t] += add;
    }
    unsigned incl = csum[t];
    unsigned excl = incl - s;
    if (excl < krem_in && krem_in <= incl) {   // exactly one owner thread
        unsigned run = excl;
        unsigned bin = 0;
        bool found = false;
#pragma unroll
        for (int j = 0; j < CHUNK; ++j) {
            unsigned nrun = run + loc[j];
            if (!found && nrun >= krem_in) { bin = (unsigned)(t * CHUNK + j); found = true; }
            if (!found) run = nrun;
        }
        sb[0] = bin;
        sb[1] = krem_in - run;
    }
    __syncthreads();
    sel_io |= sb[0] << shift;
    krem_out = sb[1];
}

__global__ __launch_bounds__(256) void k_pass1(const float* __restrict__ pred,
                                               const int* __restrict__ target,
                                               unsigned* __restrict__ ws) {
    __shared__ unsigned hist[2048];
    for (int i = threadIdx.x; i < 2048; i += 256) hist[i] = 0u;
    __syncthreads();

    float ls_spec = 0.0f, ls_tot = 0.0f;
    unsigned lc_spec = 0, lc_tot = 0;

    for (int it = 0; it < ITERS; ++it) {
        int q = it * (NBLK * 256) + blockIdx.x * 256 + threadIdx.x;  // quad index
        int pix0 = q * 4;
        int b = pix0 / HWSZ;
        int hw = pix0 - b * HWSZ;
        const float* base = pred + (size_t)b * ((size_t)CC * HWSZ) + hw;

        float x[CC][4];
#pragma unroll
        for (int c = 0; c < CC; ++c) {
            float4 v = *reinterpret_cast<const float4*>(base + (size_t)c * HWSZ);
            x[c][0] = v.x; x[c][1] = v.y; x[c][2] = v.z; x[c][3] = v.w;
        }
        int4 t4 = *reinterpret_cast<const int4*>(target + pix0);
        int tt[4] = {t4.x, t4.y, t4.z, t4.w};

        unsigned pb[4];
#pragma unroll
        for (int p = 0; p < 4; ++p) {
            int t = tt[p];
            bool valid = (t != IGNORE_LBL);
            int tc = valid ? t : 0;
            float m = x[0][p];
#pragma unroll
            for (int c = 1; c < CC; ++c) m = fmaxf(m, x[c][p]);
            float s = 0.0f;
            float xt = x[0][p];
#pragma unroll
            for (int c = 0; c < CC; ++c) {
                float v = x[c][p];
                s += expf(v - m);
                xt = (c == tc) ? v : xt;   // cndmask, no runtime-indexed array
            }
            float lp = xt - m - logf(s);
            float pr = valid ? expf(lp) : 1.0f;
            pb[p] = __float_as_uint(pr);
            atomicAdd(&hist[pb[p] >> 21], 1u);
            // speculative accumulators (no extra memory traffic)
            if (valid) {
                ls_tot += -lp; lc_tot += 1u;
                if (pr <= THR) { ls_spec += -lp; lc_spec += 1u; }
            }
        }
        *reinterpret_cast<uint4*>(ws + PROB_OFF + pix0) =
            make_uint4(pb[0], pb[1], pb[2], pb[3]);
    }

    // wave reduce the four accumulators, block reduce via LDS, 4 atomics/block
    for (int off = 32; off; off >>= 1) {
        ls_spec += __shfl_down(ls_spec, off);
        ls_tot  += __shfl_down(ls_tot, off);
        lc_spec += __shfl_down(lc_spec, off);
        lc_tot  += __shfl_down(lc_tot, off);
    }
    __shared__ float fs[2][4];
    __shared__ unsigned us[2][4];
    if ((threadIdx.x & 63) == 0) {
        int w = threadIdx.x >> 6;
        fs[0][w] = ls_spec; fs[1][w] = ls_tot;
        us[0][w] = lc_spec; us[1][w] = lc_tot;
    }
    __syncthreads();   // also orders the LDS-hist atomics before the flush below
    if (threadIdx.x == 0) {
        atomicAdd(reinterpret_cast<double*>(ws + W_SPEC_SUM),
                  (double)(fs[0][0] + fs[0][1] + fs[0][2] + fs[0][3]));
        atomicAdd(reinterpret_cast<double*>(ws + W_TOT_SUM),
                  (double)(fs[1][0] + fs[1][1] + fs[1][2] + fs[1][3]));
        atomicAdd(ws + W_SPEC_CNT, us[0][0] + us[0][1] + us[0][2] + us[0][3]);
        atomicAdd(ws + W_TOT_CNT, us[1][0] + us[1][1] + us[1][2] + us[1][3]);
    }
    // flush LDS hist once per block; rotate start to spread hot-bin atomics
    int rot = (blockIdx.x & 7) << 8;
    for (int i = threadIdx.x; i < 2048; i += 256) {
        int idx = (i + rot) & 2047;
        unsigned v = hist[idx];
        if (v) atomicAdd(ws + HIST1_OFF + idx, v);
    }
}

template <int LEVEL>
__global__ __launch_bounds__(256) void k_refine(unsigned* __restrict__ ws) {
    if (early_thr(ws + HIST1_OFF)) return;   // threshold==0.7 -> select not needed

    constexpr int NB = (LEVEL == 2) ? 2048 : 1024;
    __shared__ unsigned hist[NB];
    for (int i = threadIdx.x; i < NB; i += 256) hist[i] = 0u;
    // find_bin's leading __syncthreads covers the zero-fill above
    unsigned sel = 0, krem = 0;
    find_bin<2048>(ws + HIST1_OFF, (unsigned)KSEL, 21, sel, krem);
    if (LEVEL == 3) find_bin<2048>(ws + HIST2_OFF, krem, 10, sel, krem);

    const uint4* pbv = reinterpret_cast<const uint4*>(ws + PROB_OFF);
    for (int it = 0; it < ITERS; ++it) {
        int q = it * (NBLK * 256) + blockIdx.x * 256 + threadIdx.x;
        uint4 v = pbv[q];
        unsigned a[4] = {v.x, v.y, v.z, v.w};
#pragma unroll
        for (int p = 0; p < 4; ++p) {
            unsigned bits = a[p];
            if (LEVEL == 2) {
                if ((bits >> 21) == (sel >> 21))
                    atomicAdd(&hist[(bits >> 10) & 2047u], 1u);
            } else {
                if ((bits >> 10) == (sel >> 10))
                    atomicAdd(&hist[bits & 1023u], 1u);
            }
        }
    }
    __syncthreads();
    unsigned* gh = ws + ((LEVEL == 2) ? HIST2_OFF : HIST3_OFF);
    int rot = (blockIdx.x & 3) << 8;
    for (int i = threadIdx.x; i < NB; i += 256) {
        int idx = (i + rot) & (NB - 1);
        unsigned v = hist[idx];
        if (v) atomicAdd(gh + idx, v);
    }
}

__global__ __launch_bounds__(256) void k_final(unsigned* __restrict__ ws,
                                               const int* __restrict__ target) {
    bool early = early_thr(ws + HIST1_OFF);
    unsigned tot_cnt = ws[W_TOT_CNT];
    bool do_ohem = (tot_cnt > 0u) && (tot_cnt >= (unsigned)KSEL);
    if (blockIdx.x == 0 && threadIdx.x == 0) ws[W_EARLY] = early ? 1u : 0u;
    if (early || !do_ohem) return;           // spec/tot accumulators already hold the answer

    unsigned sel = 0, krem = 0;
    find_bin<2048>(ws + HIST1_OFF, (unsigned)KSEL, 21, sel, krem);
    find_bin<2048>(ws + HIST2_OFF, krem, 10, sel, krem);
    find_bin<1024>(ws + HIST3_OFF, krem, 0, sel, krem);
    float thr = fmaxf(__uint_as_float(sel), THR);

    const uint4* pbv = reinterpret_cast<const uint4*>(ws + PROB_OFF);
    float ls = 0.0f;
    unsigned lc = 0;
    for (int it = 0; it < ITERS; ++it) {
        int q = it * (NBLK * 256) + blockIdx.x * 256 + threadIdx.x;
        int pix0 = q * 4;
        uint4 v = pbv[q];
        int4 t4 = *reinterpret_cast<const int4*>(target + pix0);
        unsigned a[4] = {v.x, v.y, v.z, v.w};
        int tt[4] = {t4.x, t4.y, t4.z, t4.w};
#pragma unroll
        for (int p = 0; p < 4; ++p) {
            bool valid = (tt[p] != IGNORE_LBL);
            float pr = __uint_as_float(a[p]);
            bool vf = valid && (pr <= thr);
            if (vf) { ls += -logf(fmaxf(pr, 1e-37f)); lc += 1u; }
        }
    }
    for (int off = 32; off; off >>= 1) {
        ls += __shfl_down(ls, off);
        lc += __shfl_down(lc, off);
    }
    __shared__ float wsum[4];
    __shared__ unsigned wcnt[4];
    if ((threadIdx.x & 63) == 0) {
        wsum[threadIdx.x >> 6] = ls;
        wcnt[threadIdx.x >> 6] = lc;
    }
    __syncthreads();
    if (threadIdx.x == 0) {
        atomicAdd(reinterpret_cast<double*>(ws + W_SLOW_SUM),
                  (double)(wsum[0] + wsum[1] + wsum[2] + wsum[3]));
        atomicAdd(ws + W_SLOW_CNT, wcnt[0] + wcnt[1] + wcnt[2] + wcnt[3]);
    }
}

__global__ void k_finalize(const unsigned* __restrict__ ws, float* __restrict__ out) {
    if (threadIdx.x == 0 && blockIdx.x == 0) {
        unsigned tot_cnt = ws[W_TOT_CNT];
        bool do_ohem = (tot_cnt > 0u) && (tot_cnt >= (unsigned)KSEL);
        double s;
        unsigned c;
        if (!do_ohem) {
            s = *reinterpret_cast<const double*>(ws + W_TOT_SUM);  c = tot_cnt;
        } else if (ws[W_EARLY]) {
            s = *reinterpret_cast<const double*>(ws + W_SPEC_SUM); c = ws[W_SPEC_CNT];
        } else {
            s = *reinterpret_cast<const double*>(ws + W_SLOW_SUM); c = ws[W_SLOW_CNT];
        }
        unsigned d = (c > 0u) ? c : 1u;
        out[0] = (float)(s / (double)d);
    }
}

extern "C" void kernel_launch(void* const* d_in, const int* in_sizes, int n_in,
                              void* d_out, int out_size, void* d_ws, size_t ws_size,
                              hipStream_t stream) {
    const float* pred = (const float*)d_in[0];
    const int* target = (const int*)d_in[1];
    unsigned* ws = (unsigned*)d_ws;
    float* out = (float*)d_out;

    k_init<<<1, 256, 0, stream>>>(ws);
    k_pass1<<<NBLK, 256, 0, stream>>>(pred, target, ws);
    k_refine<2><<<NBLK, 256, 0, stream>>>(ws);
    k_refine<3><<<NBLK, 256, 0, stream>>>(ws);
    k_final<<<NBLK, 256, 0, stream>>>(ws, target);
    k_finalize<<<1, 64, 0, stream>>>(ws, out);
}